// Round 4
// baseline (121.313 us; speedup 1.0000x reference)
//
#include <hip/hip_runtime.h>
#include <hip/hip_bf16.h>

// Problem constants (fixed by setup_inputs): B=4096, d=128, M=8192, C=16
#define B_ROWS 4096
#define D_K    128
#define M_ROWS 8192
#define N_TOT  12288   // B_ROWS + M_ROWS
#define NJT_B  32      // B_ROWS / 128 (in-batch j-tiles)
#define NCHUNK 16      // j-chunks (grid.x)
#define JT_PER_CHUNK 6 // 96 / 16
#define NCLS   16

typedef __attribute__((ext_vector_type(8))) short short8;
typedef __attribute__((ext_vector_type(4))) float floatx4;

__device__ __forceinline__ void load_lds16(const __hip_bfloat16* g, __hip_bfloat16* l) {
    __builtin_amdgcn_global_load_lds(
        (const __attribute__((address_space(1))) void*)g,
        (__attribute__((address_space(3))) void*)l, 16, 0, 0);
}

// ---------------------------------------------------------------------------
// Kernel 1: normalize rows of f / f_neg into bf16 G[N_TOT][D_K]; fused label
// histogram (lane 0 of B-rows). One wave per row; lane holds 2 floats.
// ---------------------------------------------------------------------------
__global__ __launch_bounds__(256) void nrm_kernel(
    const float* __restrict__ f, const float* __restrict__ fneg,
    const int* __restrict__ labels, __hip_bfloat16* __restrict__ G,
    int* __restrict__ hist)
{
    const int wave = threadIdx.x >> 6;
    const int lane = threadIdx.x & 63;
    const int row  = blockIdx.x * 4 + wave;           // grid exact: 3072*4
    const float* src = (row < B_ROWS) ? (f + (size_t)row * D_K)
                                      : (fneg + (size_t)(row - B_ROWS) * D_K);
    float2 v = *reinterpret_cast<const float2*>(src + lane * 2);
    float ss = v.x * v.x + v.y * v.y;
    #pragma unroll
    for (int m = 1; m < 64; m <<= 1) ss += __shfl_xor(ss, m, 64);
    const float scale = 1.0f / fmaxf(sqrtf(ss), 1e-8f);   // 1/max(||x||, EPS)
    __hip_bfloat162 o;
    o.x = __float2bfloat16(v.x * scale);
    o.y = __float2bfloat16(v.y * scale);
    *reinterpret_cast<__hip_bfloat162*>(G + (size_t)row * D_K + lane * 2) = o;
    if (row < B_ROWS && lane == 0) atomicAdd(&hist[labels[row]], 1);
}

// ---------------------------------------------------------------------------
// Kernel 2: per-class sums S[c][d] = sum over in-batch rows j with lab=c of
// G[j][d] (f32). 32 blocks x 256 thr; block handles a 128-row stripe via an
// LDS partial (8KB), then global atomicAdd merge (2048 addrs x 32 blocks).
// ---------------------------------------------------------------------------
__global__ __launch_bounds__(256) void csum_kernel(
    const __hip_bfloat16* __restrict__ G, const int* __restrict__ labels,
    float* __restrict__ S)
{
    __shared__ float Sp[NCLS * D_K];
    const int tid = threadIdx.x;
    #pragma unroll
    for (int k = 0; k < NCLS * D_K / 256; ++k) Sp[tid + k * 256] = 0.f;
    __syncthreads();

    const int d    = tid & 127;
    const int half = tid >> 7;
    const int j0   = blockIdx.x * 128;
    for (int jj = half; jj < 128; jj += 2) {
        const int j = j0 + jj;
        const int c = labels[j];
        const float v = __bfloat162float(G[(size_t)j * D_K + d]);
        atomicAdd(&Sp[c * D_K + d], v);
    }
    __syncthreads();
    #pragma unroll
    for (int k = 0; k < NCLS * D_K / 256; ++k) {
        const int idx = tid + k * 256;
        atomicAdd(&S[idx], Sp[idx]);
    }
}

// ---------------------------------------------------------------------------
// Kernel 3: pure branch-free exp-sum GEMM (self-exclusion & labels moved to
// fin). Grid (16, 32). Block 128i x 128j, 4 waves, wave tile 64x64.
// A fragments register-resident; B tiles double-buffered in LDS via LINEAR
// global_load_lds w=16 (m97 pattern — linear source, linear dest).
// Fragment layouts (verified R1-R3):
//   A/B: row = lane&15, k = (lane>>4)*8 + e (contiguous bf16x8)
//   C/D: col(j) = lane&15, row(i) = (lane>>4)*4 + reg
// Output: part_d[row*32 + slice], slice = jc*2 + wj  (transposed for fin).
// ---------------------------------------------------------------------------
__global__ __launch_bounds__(256, 2) void sim_kernel(
    const __hip_bfloat16* __restrict__ G, float* __restrict__ part_d)
{
    __shared__ __hip_bfloat16 Bs[2][128 * 128];   // 2 x 32KB

    const int jc   = blockIdx.x;          // 0..15
    const int it   = blockIdx.y;          // 0..31
    const int tid  = threadIdx.x;
    const int wave = tid >> 6;
    const int lane = tid & 63;
    const int wi   = wave >> 1;           // 0..1
    const int wj   = wave & 1;            // 0..1
    const int i0   = it * 128 + wi * 64;

    const int r16 = lane & 15;
    const int grp = lane >> 4;

    // resident A fragments [a][ks] (one-time gather from L2)
    const __hip_bfloat16* Arow = G + (size_t)(i0 + r16) * D_K + grp * 8;
    short8 afr[4][4];
    #pragma unroll
    for (int a = 0; a < 4; ++a)
        #pragma unroll
        for (int ks = 0; ks < 4; ++ks)
            afr[a][ks] = *reinterpret_cast<const short8*>(
                Arow + (size_t)a * 16 * D_K + ks * 32);

    float dsum[4][4];
    #pragma unroll
    for (int a = 0; a < 4; ++a)
        #pragma unroll
        for (int r = 0; r < 4; ++r) dsum[a][r] = 0.f;

    // linear per-lane staging offset (elements) within a 128x128 bf16 tile
    const int stoff = (wave * 8) * 512 + lane * 8;   // + s*512 per instr

    // prologue: stage tile 0 into buf 0
    {
        const __hip_bfloat16* src = G + (size_t)(jc * JT_PER_CHUNK) * 128 * D_K;
        #pragma unroll
        for (int s = 0; s < 8; ++s)
            load_lds16(src + stoff + s * 512, &Bs[0][(wave * 8 + s) * 512]);
    }

    for (int t = 0; t < JT_PER_CHUNK; ++t) {
        const int jt  = jc * JT_PER_CHUNK + t;
        const int cur = t & 1;
        __syncthreads();   // buf[cur] staged (vmcnt drain); prev compute done

        if (t + 1 < JT_PER_CHUNK) {
            const __hip_bfloat16* src = G + (size_t)(jt + 1) * 128 * D_K;
            #pragma unroll
            for (int s = 0; s < 8; ++s)
                load_lds16(src + stoff + s * 512, &Bs[cur ^ 1][(wave * 8 + s) * 512]);
        }

        floatx4 acc[4][4];
        #pragma unroll
        for (int a = 0; a < 4; ++a)
            #pragma unroll
            for (int b = 0; b < 4; ++b)
                acc[a][b] = (floatx4){0.f, 0.f, 0.f, 0.f};

        const char* base = (const char*)&Bs[cur][0];
        #pragma unroll
        for (int ks = 0; ks < 4; ++ks) {
            short8 bfr[4];
            #pragma unroll
            for (int b = 0; b < 4; ++b) {
                const int jloc = wj * 64 + b * 16 + r16;
                bfr[b] = *reinterpret_cast<const short8*>(
                    base + jloc * 256 + (ks * 4 + grp) * 16);
            }
            #pragma unroll
            for (int a = 0; a < 4; ++a)
                #pragma unroll
                for (int b = 0; b < 4; ++b)
                    acc[a][b] = __builtin_amdgcn_mfma_f32_16x16x32_bf16(
                        afr[a][ks], bfr[b], acc[a][b], 0, 0, 0);
        }

        // branch-free epilogue: exp-sum everything (self handled in fin)
        #pragma unroll
        for (int a = 0; a < 4; ++a)
            #pragma unroll
            for (int r = 0; r < 4; ++r) {
                float s0 = __expf(acc[a][0][r]) + __expf(acc[a][1][r]);
                float s1 = __expf(acc[a][2][r]) + __expf(acc[a][3][r]);
                dsum[a][r] += s0 + s1;
            }
    }

    // 16-lane (column-group) reduce
    #pragma unroll
    for (int a = 0; a < 4; ++a)
        #pragma unroll
        for (int r = 0; r < 4; ++r) {
            #pragma unroll
            for (int m = 1; m < 16; m <<= 1)
                dsum[a][r] += __shfl_xor(dsum[a][r], m, 64);
        }
    if (r16 == 0) {
        const int slice = jc * 2 + wj;
        #pragma unroll
        for (int a = 0; a < 4; ++a)
            #pragma unroll
            for (int r = 0; r < 4; ++r)
                part_d[(size_t)(i0 + a * 16 + grp * 4 + r) * 32 + slice] =
                    dsum[a][r];
    }
}

// ---------------------------------------------------------------------------
// Kernel 4: finalize. 64 blocks x 4 waves; each wave owns 16 rows.
// Per row: denom = sum(part) - exp(selfdot); psum = <g_i, S[lab]> - selfdot;
// loss = log(denom) - psum/npos. Block reduce -> atomicAdd(out, mean part).
// ---------------------------------------------------------------------------
__global__ __launch_bounds__(256) void fin_kernel(
    const __hip_bfloat16* __restrict__ G, const float* __restrict__ part_d,
    const float* __restrict__ S, const int* __restrict__ labels,
    const int* __restrict__ hist, float* __restrict__ out)
{
    const int tid  = threadIdx.x;
    const int wave = tid >> 6;
    const int lane = tid & 63;

    float lsum = 0.f;
    for (int rr = 0; rr < 16; ++rr) {
        const int i   = (blockIdx.x * 4 + wave) * 16 + rr;
        const int lab = labels[i];
        float pd = (lane < 32) ? part_d[(size_t)i * 32 + lane] : 0.f;
        __hip_bfloat162 g2 = *reinterpret_cast<const __hip_bfloat162*>(
            G + (size_t)i * D_K + lane * 2);
        const float f0 = __bfloat162float(g2.x);
        const float f1 = __bfloat162float(g2.y);
        float2 sv = *reinterpret_cast<const float2*>(S + lab * D_K + lane * 2);
        float self = f0 * f0 + f1 * f1;
        float sp   = f0 * sv.x + f1 * sv.y;
        #pragma unroll
        for (int m = 1; m < 64; m <<= 1) {
            pd   += __shfl_xor(pd, m, 64);
            self += __shfl_xor(self, m, 64);
            sp   += __shfl_xor(sp, m, 64);
        }
        if (lane == 0) {
            const float npos  = (float)(hist[lab] - 1);
            const float denom = pd - __expf(self);
            lsum += __logf(denom) - (sp - self) / npos;
        }
    }
    __shared__ float w4[4];
    if (lane == 0) w4[wave] = lsum;
    __syncthreads();
    if (tid == 0)
        atomicAdd(out, (w4[0] + w4[1] + w4[2] + w4[3]) * (1.0f / (float)B_ROWS));
}

// ---------------------------------------------------------------------------
extern "C" void kernel_launch(void* const* d_in, const int* in_sizes, int n_in,
                              void* d_out, int out_size, void* d_ws, size_t ws_size,
                              hipStream_t stream) {
    const float* f      = (const float*)d_in[0];
    const float* fneg   = (const float*)d_in[1];
    const int*   labels = (const int*)d_in[2];
    float*       out    = (float*)d_out;

    char* ws = (char*)d_ws;
    // Workspace layout (bytes):
    //   G      : 12288*128*2 = 3,145,728
    //   part_d : 4096*32*4   =   524,288
    //   S      : 16*128*4    =     8,192
    //   hist   : 16*4 (pad 64)
    __hip_bfloat16* G      = (__hip_bfloat16*)(ws);
    float*          part_d = (float*)(ws + 3145728);
    float*          S      = (float*)(ws + 3145728 + 524288);
    int*            hist   = (int*)(ws + 3145728 + 524288 + 8192);

    hipMemsetAsync(S, 0, 8192 + 64, stream);   // S + hist contiguous
    hipMemsetAsync(out, 0, sizeof(float), stream);

    nrm_kernel<<<N_TOT / 4, 256, 0, stream>>>(f, fneg, labels, G, hist);
    csum_kernel<<<B_ROWS / 128, 256, 0, stream>>>(G, labels, S);

    dim3 gridS(NCHUNK, 32);   // (16, 32) = 512 blocks, 2/CU
    sim_kernel<<<gridS, 256, 0, stream>>>(G, part_d);

    fin_kernel<<<64, 256, 0, stream>>>(G, part_d, S, labels, hist, out);
}

// Round 5
// 63.880 us; speedup vs baseline: 1.8991x; 1.8991x over previous
//
#include <hip/hip_runtime.h>
#include <hip/hip_bf16.h>

// Problem constants (fixed by setup_inputs): B=4096, d=128, M=8192, C=16
#define B_ROWS 4096
#define D_K    128
#define M_ROWS 8192
#define N_TOT  12288   // B_ROWS + M_ROWS
#define NCHUNK 16      // j-chunks (grid.x of sim)
#define JT_PER_CHUNK 6 // 96 / 16
#define NCLS   16

typedef __attribute__((ext_vector_type(8))) short short8;
typedef __attribute__((ext_vector_type(4))) float floatx4;

// ---------------------------------------------------------------------------
// Kernel 0: init. Zeros S (2048 f32), hist (16 int), out (1 f32). One block.
// ---------------------------------------------------------------------------
__global__ __launch_bounds__(256) void init_kernel(
    float* __restrict__ S, int* __restrict__ hist, float* __restrict__ out)
{
    const int tid = threadIdx.x;
    #pragma unroll
    for (int k = 0; k < 8; ++k) S[tid + k * 256] = 0.f;
    if (tid < NCLS) hist[tid] = 0;
    if (tid == 0) out[0] = 0.f;
}

// ---------------------------------------------------------------------------
// Kernel 1: normalize rows of f / f_neg into bf16 G[N_TOT][D_K].
// One wave per row; lane holds 2 floats. NO atomics (R4 lesson: 4096
// device-scope atomics onto 16 addresses cost ~40 µs).
// ---------------------------------------------------------------------------
__global__ __launch_bounds__(256) void nrm_kernel(
    const float* __restrict__ f, const float* __restrict__ fneg,
    __hip_bfloat16* __restrict__ G)
{
    const int wave = threadIdx.x >> 6;
    const int lane = threadIdx.x & 63;
    const int row  = blockIdx.x * 4 + wave;           // grid exact: 3072*4
    const float* src = (row < B_ROWS) ? (f + (size_t)row * D_K)
                                      : (fneg + (size_t)(row - B_ROWS) * D_K);
    float2 v = *reinterpret_cast<const float2*>(src + lane * 2);
    float ss = v.x * v.x + v.y * v.y;
    #pragma unroll
    for (int m = 1; m < 64; m <<= 1) ss += __shfl_xor(ss, m, 64);
    const float scale = 1.0f / fmaxf(sqrtf(ss), 1e-8f);   // 1/max(||x||, EPS)
    __hip_bfloat162 o;
    o.x = __float2bfloat16(v.x * scale);
    o.y = __float2bfloat16(v.y * scale);
    *reinterpret_cast<__hip_bfloat162*>(G + (size_t)row * D_K + lane * 2) = o;
}

// ---------------------------------------------------------------------------
// Kernel 2: per-class sums S[c][d] (f32) + label histogram.
// 32 blocks x 256 thr; block owns a 128-row stripe; LDS partial (8KB) via LDS
// atomics, then global atomicAdd merge (2048 addrs x 32 blocks; 16-bin hist
// merged with 16 atomics per block).
// ---------------------------------------------------------------------------
__global__ __launch_bounds__(256) void csum_kernel(
    const __hip_bfloat16* __restrict__ G, const int* __restrict__ labels,
    float* __restrict__ S, int* __restrict__ hist)
{
    __shared__ float Sp[NCLS * D_K];
    __shared__ int   lh[NCLS];
    const int tid = threadIdx.x;
    #pragma unroll
    for (int k = 0; k < NCLS * D_K / 256; ++k) Sp[tid + k * 256] = 0.f;
    if (tid < NCLS) lh[tid] = 0;
    __syncthreads();

    const int j0 = blockIdx.x * 128;
    if (tid < 128) atomicAdd(&lh[labels[j0 + tid]], 1);

    const int d    = tid & 127;
    const int half = tid >> 7;
    for (int jj = half; jj < 128; jj += 2) {
        const int j = j0 + jj;
        const int c = labels[j];
        const float v = __bfloat162float(G[(size_t)j * D_K + d]);
        atomicAdd(&Sp[c * D_K + d], v);
    }
    __syncthreads();
    #pragma unroll
    for (int k = 0; k < NCLS * D_K / 256; ++k) {
        const int idx = tid + k * 256;
        atomicAdd(&S[idx], Sp[idx]);
    }
    if (tid < NCLS) atomicAdd(&hist[tid], lh[tid]);
}

// ---------------------------------------------------------------------------
// Kernel 3: branch-free exp-sum GEMM.
// Grid (16, 32). Block 128i x 128j, 4 waves, wave tile 64x64 (acc 4x4).
// A fragments register-resident. B tiles double-buffered in LDS:
//   stage  = global->reg (source granule pre-swizzled g = col ^ (row&7),
//            per-wave footprint still 1KB contiguous -> no amplification)
//            + LINEAR ds_write_b128 (conflict-free)
//   read   = ds_read_b128 at slot = (ks*4+grp) ^ (r16&7): 8 lanes per 16B
//            bank-slot, uniform -> b128 floor, conflict-free.
// Loads for tile t+1 issue right after the barrier, fly under compute(t);
// ds_write after compute. One barrier per tile.
// Fragment layouts (verified R1-R4):
//   A/B: row = lane&15, k = (lane>>4)*8 + e (contiguous bf16x8)
//   C/D: col(j) = lane&15, row(i) = (lane>>4)*4 + reg
// ---------------------------------------------------------------------------
__global__ __launch_bounds__(256, 2) void sim_kernel(
    const __hip_bfloat16* __restrict__ G, float* __restrict__ part_d)
{
    __shared__ __hip_bfloat16 Bs[2][128 * 128];   // 2 x 32KB

    const int jc   = blockIdx.x;          // 0..15
    const int it   = blockIdx.y;          // 0..31
    const int tid  = threadIdx.x;
    const int wave = tid >> 6;
    const int lane = tid & 63;
    const int wi   = wave >> 1;           // 0..1
    const int wj   = wave & 1;            // 0..1
    const int i0   = it * 128 + wi * 64;

    const int r16 = lane & 15;
    const int grp = lane >> 4;

    // resident A fragments [a][ks] (one-time gather from L2)
    const __hip_bfloat16* Arow = G + (size_t)(i0 + r16) * D_K + grp * 8;
    short8 afr[4][4];
    #pragma unroll
    for (int a = 0; a < 4; ++a)
        #pragma unroll
        for (int ks = 0; ks < 4; ++ks)
            afr[a][ks] = *reinterpret_cast<const short8*>(
                Arow + (size_t)a * 16 * D_K + ks * 32);

    float dsum[4][4];
    #pragma unroll
    for (int a = 0; a < 4; ++a)
        #pragma unroll
        for (int r = 0; r < 4; ++r) dsum[a][r] = 0.f;

    // per-round swizzled SOURCE offsets (elements); LDS side stays linear.
    // LDS byte p = s*4096 + tid*16 -> row = p>>8, slot = (p>>4)&15;
    // stored granule = slot ^ (row&7).
    int srcoff[8];
    #pragma unroll
    for (int s = 0; s < 8; ++s) {
        const int row  = s * 16 + (tid >> 4);
        const int gran = (tid & 15) ^ (row & 7);
        srcoff[s] = row * D_K + gran * 8;
    }

    short8 streg[8];
    // prologue: load + write tile 0 into buf 0
    {
        const __hip_bfloat16* src = G + (size_t)(jc * JT_PER_CHUNK) * 128 * D_K;
        #pragma unroll
        for (int s = 0; s < 8; ++s)
            streg[s] = *reinterpret_cast<const short8*>(src + srcoff[s]);
        #pragma unroll
        for (int s = 0; s < 8; ++s)
            *reinterpret_cast<short8*>((char*)&Bs[0][0] + s * 4096 + tid * 16) =
                streg[s];
    }

    for (int t = 0; t < JT_PER_CHUNK; ++t) {
        const int cur = t & 1;
        __syncthreads();   // buf[cur] written & visible; buf[cur^1] reads done

        if (t + 1 < JT_PER_CHUNK) {
            const __hip_bfloat16* src =
                G + (size_t)(jc * JT_PER_CHUNK + t + 1) * 128 * D_K;
            #pragma unroll
            for (int s = 0; s < 8; ++s)
                streg[s] = *reinterpret_cast<const short8*>(src + srcoff[s]);
        }

        floatx4 acc[4][4];
        #pragma unroll
        for (int a = 0; a < 4; ++a)
            #pragma unroll
            for (int b = 0; b < 4; ++b)
                acc[a][b] = (floatx4){0.f, 0.f, 0.f, 0.f};

        const char* base = (const char*)&Bs[cur][0];
        #pragma unroll
        for (int ks = 0; ks < 4; ++ks) {
            const int slot = (ks * 4 + grp) ^ (r16 & 7);
            short8 bfr[4];
            #pragma unroll
            for (int b = 0; b < 4; ++b) {
                const int jloc = wj * 64 + b * 16 + r16;
                bfr[b] = *reinterpret_cast<const short8*>(
                    base + jloc * 256 + slot * 16);
            }
            #pragma unroll
            for (int a = 0; a < 4; ++a)
                #pragma unroll
                for (int b = 0; b < 4; ++b)
                    acc[a][b] = __builtin_amdgcn_mfma_f32_16x16x32_bf16(
                        afr[a][ks], bfr[b], acc[a][b], 0, 0, 0);
        }

        // branch-free epilogue: exp-sum everything (self handled in fin)
        #pragma unroll
        for (int a = 0; a < 4; ++a)
            #pragma unroll
            for (int r = 0; r < 4; ++r) {
                float s0 = __expf(acc[a][0][r]) + __expf(acc[a][1][r]);
                float s1 = __expf(acc[a][2][r]) + __expf(acc[a][3][r]);
                dsum[a][r] += s0 + s1;
            }

        if (t + 1 < JT_PER_CHUNK) {
            #pragma unroll
            for (int s = 0; s < 8; ++s)
                *reinterpret_cast<short8*>(
                    (char*)&Bs[cur ^ 1][0] + s * 4096 + tid * 16) = streg[s];
        }
    }

    // 16-lane (column-group) reduce
    #pragma unroll
    for (int a = 0; a < 4; ++a)
        #pragma unroll
        for (int r = 0; r < 4; ++r) {
            #pragma unroll
            for (int m = 1; m < 16; m <<= 1)
                dsum[a][r] += __shfl_xor(dsum[a][r], m, 64);
        }
    if (r16 == 0) {
        const int slice = jc * 2 + wj;
        #pragma unroll
        for (int a = 0; a < 4; ++a)
            #pragma unroll
            for (int r = 0; r < 4; ++r)
                part_d[(size_t)(i0 + a * 16 + grp * 4 + r) * 32 + slice] =
                    dsum[a][r];
    }
}

// ---------------------------------------------------------------------------
// Kernel 4: finalize. 128 blocks x 4 waves; each wave owns 8 rows.
// Per row: denom = sum(part) - exp(selfdot); psum = <g_i, S[lab]> - selfdot;
// loss = log(denom) - psum/npos. Block reduce -> atomicAdd(out, mean part).
// ---------------------------------------------------------------------------
__global__ __launch_bounds__(256) void fin_kernel(
    const __hip_bfloat16* __restrict__ G, const float* __restrict__ part_d,
    const float* __restrict__ S, const int* __restrict__ labels,
    const int* __restrict__ hist, float* __restrict__ out)
{
    const int tid  = threadIdx.x;
    const int wave = tid >> 6;
    const int lane = tid & 63;

    float lsum = 0.f;
    #pragma unroll 2
    for (int rr = 0; rr < 8; ++rr) {
        const int i   = (blockIdx.x * 4 + wave) * 8 + rr;
        const int lab = labels[i];
        float pd = (lane < 32) ? part_d[(size_t)i * 32 + lane] : 0.f;
        __hip_bfloat162 g2 = *reinterpret_cast<const __hip_bfloat162*>(
            G + (size_t)i * D_K + lane * 2);
        const float f0 = __bfloat162float(g2.x);
        const float f1 = __bfloat162float(g2.y);
        float2 sv = *reinterpret_cast<const float2*>(S + lab * D_K + lane * 2);
        float self = f0 * f0 + f1 * f1;
        float sp   = f0 * sv.x + f1 * sv.y;
        #pragma unroll
        for (int m = 1; m < 64; m <<= 1) {
            pd   += __shfl_xor(pd, m, 64);
            self += __shfl_xor(self, m, 64);
            sp   += __shfl_xor(sp, m, 64);
        }
        if (lane == 0) {
            const float npos  = (float)(hist[lab] - 1);
            const float denom = pd - __expf(self);
            lsum += __logf(denom) - (sp - self) / npos;
        }
    }
    __shared__ float w4[4];
    if (lane == 0) w4[wave] = lsum;
    __syncthreads();
    if (tid == 0)
        atomicAdd(out, (w4[0] + w4[1] + w4[2] + w4[3]) * (1.0f / (float)B_ROWS));
}

// ---------------------------------------------------------------------------
extern "C" void kernel_launch(void* const* d_in, const int* in_sizes, int n_in,
                              void* d_out, int out_size, void* d_ws, size_t ws_size,
                              hipStream_t stream) {
    const float* f      = (const float*)d_in[0];
    const float* fneg   = (const float*)d_in[1];
    const int*   labels = (const int*)d_in[2];
    float*       out    = (float*)d_out;

    char* ws = (char*)d_ws;
    // Workspace layout (bytes):
    //   G      : 12288*128*2 = 3,145,728
    //   part_d : 4096*32*4   =   524,288
    //   S      : 16*128*4    =     8,192
    //   hist   : 16*4
    __hip_bfloat16* G      = (__hip_bfloat16*)(ws);
    float*          part_d = (float*)(ws + 3145728);
    float*          S      = (float*)(ws + 3145728 + 524288);
    int*            hist   = (int*)(ws + 3145728 + 524288 + 8192);

    init_kernel<<<1, 256, 0, stream>>>(S, hist, out);
    nrm_kernel<<<N_TOT / 4, 256, 0, stream>>>(f, fneg, G);
    csum_kernel<<<B_ROWS / 128, 256, 0, stream>>>(G, labels, S, hist);

    dim3 gridS(NCHUNK, 32);   // (16, 32) = 512 blocks, 2/CU
    sim_kernel<<<gridS, 256, 0, stream>>>(G, part_d);

    fin_kernel<<<128, 256, 0, stream>>>(G, part_d, S, labels, hist, out);
}

// Round 6
// 62.072 us; speedup vs baseline: 1.9544x; 1.0291x over previous
//
#include <hip/hip_runtime.h>
#include <hip/hip_bf16.h>

// Problem constants (fixed by setup_inputs): B=4096, d=128, M=8192, C=16
#define B_ROWS 4096
#define D_K    128
#define M_ROWS 8192
#define N_TOT  12288   // B_ROWS + M_ROWS
#define NCHUNK 16      // j-chunks (grid.x of sim)
#define JT_PER_CHUNK 6 // 96 / 16
#define NCLS   16

typedef __attribute__((ext_vector_type(8))) short short8;
typedef __attribute__((ext_vector_type(4))) float floatx4;

// ---------------------------------------------------------------------------
// Kernel 1: normalize rows of f / f_neg into bf16 G[N_TOT][D_K].
// One wave per row; lane holds 2 floats. Block 0 additionally zeros
// S / hist / out (replaces the init kernel; csum runs strictly after).
// ---------------------------------------------------------------------------
__global__ __launch_bounds__(256) void nrm_kernel(
    const float* __restrict__ f, const float* __restrict__ fneg,
    __hip_bfloat16* __restrict__ G, float* __restrict__ S,
    int* __restrict__ hist, float* __restrict__ out)
{
    const int tid  = threadIdx.x;
    const int wave = tid >> 6;
    const int lane = tid & 63;
    const int row  = blockIdx.x * 4 + wave;           // grid exact: 3072*4
    if (blockIdx.x == 0) {
        #pragma unroll
        for (int k = 0; k < 8; ++k) S[tid + k * 256] = 0.f;
        if (tid < NCLS) hist[tid] = 0;
        if (tid == 0) out[0] = 0.f;
    }
    const float* src = (row < B_ROWS) ? (f + (size_t)row * D_K)
                                      : (fneg + (size_t)(row - B_ROWS) * D_K);
    float2 v = *reinterpret_cast<const float2*>(src + lane * 2);
    float ss = v.x * v.x + v.y * v.y;
    #pragma unroll
    for (int m = 1; m < 64; m <<= 1) ss += __shfl_xor(ss, m, 64);
    const float scale = 1.0f / fmaxf(sqrtf(ss), 1e-8f);   // 1/max(||x||, EPS)
    __hip_bfloat162 o;
    o.x = __float2bfloat16(v.x * scale);
    o.y = __float2bfloat16(v.y * scale);
    *reinterpret_cast<__hip_bfloat162*>(G + (size_t)row * D_K + lane * 2) = o;
}

// ---------------------------------------------------------------------------
// Kernel 2: per-class sums S[c][d] (f32) + label histogram.
// 32 blocks x 256 thr; block owns a 128-row stripe; LDS partials, then
// global atomicAdd merge. Loads vectorized 2-wide (bf16x2).
// ---------------------------------------------------------------------------
__global__ __launch_bounds__(256) void csum_kernel(
    const __hip_bfloat16* __restrict__ G, const int* __restrict__ labels,
    float* __restrict__ S, int* __restrict__ hist)
{
    __shared__ float Sp[NCLS * D_K];
    __shared__ int   lh[NCLS];
    const int tid = threadIdx.x;
    #pragma unroll
    for (int k = 0; k < NCLS * D_K / 256; ++k) Sp[tid + k * 256] = 0.f;
    if (tid < NCLS) lh[tid] = 0;
    __syncthreads();

    const int j0 = blockIdx.x * 128;
    if (tid < 128) atomicAdd(&lh[labels[j0 + tid]], 1);

    const int d2 = (tid & 63) * 2;
    const int q  = tid >> 6;               // 0..3
    for (int jj = q; jj < 128; jj += 4) {
        const int j = j0 + jj;
        const int c = labels[j];
        __hip_bfloat162 v = *reinterpret_cast<const __hip_bfloat162*>(
            G + (size_t)j * D_K + d2);
        atomicAdd(&Sp[c * D_K + d2],     __bfloat162float(v.x));
        atomicAdd(&Sp[c * D_K + d2 + 1], __bfloat162float(v.y));
    }
    __syncthreads();
    #pragma unroll
    for (int k = 0; k < NCLS * D_K / 256; ++k) {
        const int idx = tid + k * 256;
        atomicAdd(&S[idx], Sp[idx]);
    }
    if (tid < NCLS) atomicAdd(&hist[tid], lh[tid]);
}

// ---------------------------------------------------------------------------
// Kernel 3: branch-free exp-sum GEMM, occupancy-tuned.
// Grid (16, 32). Block = 512 thr = 8 waves; block tile 128i x 128j.
// Wave (wi,wj) owns 32x64: afr[2][4] resident, acc 2x4 (~115 VGPR total);
// __launch_bounds__(512,4) caps VGPR at 128 -> 16 waves/CU (4/SIMD) so the
// exp/VALU epilogue and barrier drains hide under other waves' MFMAs.
// B tiles double-buffered in LDS; stage = global->reg (pre-swizzled source
// granule g = col ^ (row&7), verified R5) + linear ds_write_b128;
// read = ds_read_b128 at slot=(ks*4+grp)^(r16&7) (2-way max = free, m136).
// Fragment layouts (verified R1-R5):
//   A/B: row = lane&15, k = (lane>>4)*8 + e (contiguous bf16x8)
//   C/D: col(j) = lane&15, row(i) = (lane>>4)*4 + reg
// ---------------------------------------------------------------------------
__global__ __launch_bounds__(512, 4) void sim_kernel(
    const __hip_bfloat16* __restrict__ G, float* __restrict__ part_d)
{
    __shared__ __hip_bfloat16 Bs[2][128 * 128];   // 2 x 32KB

    const int jc   = blockIdx.x;          // 0..15
    const int it   = blockIdx.y;          // 0..31
    const int tid  = threadIdx.x;         // 0..511
    const int wave = tid >> 6;            // 0..7
    const int lane = tid & 63;
    const int wi   = wave >> 1;           // 0..3 : i-quarter (32 rows)
    const int wj   = wave & 1;            // 0..1 : j-half (64 cols)
    const int i0   = it * 128 + wi * 32;

    const int r16 = lane & 15;
    const int grp = lane >> 4;

    // resident A fragments [a][ks] (one-time gather from L2)
    const __hip_bfloat16* Arow = G + (size_t)(i0 + r16) * D_K + grp * 8;
    short8 afr[2][4];
    #pragma unroll
    for (int a = 0; a < 2; ++a)
        #pragma unroll
        for (int ks = 0; ks < 4; ++ks)
            afr[a][ks] = *reinterpret_cast<const short8*>(
                Arow + (size_t)a * 16 * D_K + ks * 32);

    float dsum[2][4];
    #pragma unroll
    for (int a = 0; a < 2; ++a)
        #pragma unroll
        for (int r = 0; r < 4; ++r) dsum[a][r] = 0.f;

    // staging: 512 thr x 16B = 8KB per round, 4 rounds per 32KB tile.
    // LDS byte p = s*8192 + tid*16 -> row = p>>8, slot = (p>>4)&15;
    // source granule pre-swizzled: gran = slot ^ (row&7).
    int srcoff[4];
    #pragma unroll
    for (int s = 0; s < 4; ++s) {
        const int row  = s * 32 + (tid >> 4);
        const int gran = (tid & 15) ^ (row & 7);
        srcoff[s] = row * D_K + gran * 8;
    }

    short8 streg[4];
    // prologue: load + write tile 0 into buf 0
    {
        const __hip_bfloat16* src = G + (size_t)(jc * JT_PER_CHUNK) * 128 * D_K;
        #pragma unroll
        for (int s = 0; s < 4; ++s)
            streg[s] = *reinterpret_cast<const short8*>(src + srcoff[s]);
        #pragma unroll
        for (int s = 0; s < 4; ++s)
            *reinterpret_cast<short8*>((char*)&Bs[0][0] + s * 8192 + tid * 16) =
                streg[s];
    }

    for (int t = 0; t < JT_PER_CHUNK; ++t) {
        const int cur = t & 1;
        __syncthreads();   // buf[cur] written & visible; buf[cur^1] reads done

        if (t + 1 < JT_PER_CHUNK) {
            const __hip_bfloat16* src =
                G + (size_t)(jc * JT_PER_CHUNK + t + 1) * 128 * D_K;
            #pragma unroll
            for (int s = 0; s < 4; ++s)
                streg[s] = *reinterpret_cast<const short8*>(src + srcoff[s]);
        }

        floatx4 acc[2][4];
        #pragma unroll
        for (int a = 0; a < 2; ++a)
            #pragma unroll
            for (int b = 0; b < 4; ++b)
                acc[a][b] = (floatx4){0.f, 0.f, 0.f, 0.f};

        const char* base = (const char*)&Bs[cur][0];
        #pragma unroll
        for (int ks = 0; ks < 4; ++ks) {
            const int slot = (ks * 4 + grp) ^ (r16 & 7);
            short8 bfr[4];
            #pragma unroll
            for (int b = 0; b < 4; ++b) {
                const int jloc = wj * 64 + b * 16 + r16;
                bfr[b] = *reinterpret_cast<const short8*>(
                    base + jloc * 256 + slot * 16);
            }
            #pragma unroll
            for (int a = 0; a < 2; ++a)
                #pragma unroll
                for (int b = 0; b < 4; ++b)
                    acc[a][b] = __builtin_amdgcn_mfma_f32_16x16x32_bf16(
                        afr[a][ks], bfr[b], acc[a][b], 0, 0, 0);
        }

        // branch-free epilogue: exp-sum everything (self handled in fin)
        #pragma unroll
        for (int a = 0; a < 2; ++a)
            #pragma unroll
            for (int r = 0; r < 4; ++r) {
                float s0 = __expf(acc[a][0][r]) + __expf(acc[a][1][r]);
                float s1 = __expf(acc[a][2][r]) + __expf(acc[a][3][r]);
                dsum[a][r] += s0 + s1;
            }

        if (t + 1 < JT_PER_CHUNK) {
            #pragma unroll
            for (int s = 0; s < 4; ++s)
                *reinterpret_cast<short8*>(
                    (char*)&Bs[cur ^ 1][0] + s * 8192 + tid * 16) = streg[s];
        }
    }

    // 16-lane (column-group) reduce
    #pragma unroll
    for (int a = 0; a < 2; ++a)
        #pragma unroll
        for (int r = 0; r < 4; ++r) {
            #pragma unroll
            for (int m = 1; m < 16; m <<= 1)
                dsum[a][r] += __shfl_xor(dsum[a][r], m, 64);
        }
    if (r16 == 0) {
        const int slice = jc * 2 + wj;
        #pragma unroll
        for (int a = 0; a < 2; ++a)
            #pragma unroll
            for (int r = 0; r < 4; ++r)
                part_d[(size_t)(i0 + a * 16 + grp * 4 + r) * 32 + slice] =
                    dsum[a][r];
    }
}

// ---------------------------------------------------------------------------
// Kernel 4: finalize. 128 blocks x 4 waves; each wave owns 8 rows.
// Per row: denom = sum(part) - exp(selfdot); psum = <g_i, S[lab]> - selfdot;
// loss = log(denom) - psum/npos. Block reduce -> atomicAdd(out, mean part).
// ---------------------------------------------------------------------------
__global__ __launch_bounds__(256) void fin_kernel(
    const __hip_bfloat16* __restrict__ G, const float* __restrict__ part_d,
    const float* __restrict__ S, const int* __restrict__ labels,
    const int* __restrict__ hist, float* __restrict__ out)
{
    const int tid  = threadIdx.x;
    const int wave = tid >> 6;
    const int lane = tid & 63;

    float lsum = 0.f;
    #pragma unroll 2
    for (int rr = 0; rr < 8; ++rr) {
        const int i   = (blockIdx.x * 4 + wave) * 8 + rr;
        const int lab = labels[i];
        float pd = (lane < 32) ? part_d[(size_t)i * 32 + lane] : 0.f;
        __hip_bfloat162 g2 = *reinterpret_cast<const __hip_bfloat162*>(
            G + (size_t)i * D_K + lane * 2);
        const float f0 = __bfloat162float(g2.x);
        const float f1 = __bfloat162float(g2.y);
        float2 sv = *reinterpret_cast<const float2*>(S + lab * D_K + lane * 2);
        float self = f0 * f0 + f1 * f1;
        float sp   = f0 * sv.x + f1 * sv.y;
        #pragma unroll
        for (int m = 1; m < 64; m <<= 1) {
            pd   += __shfl_xor(pd, m, 64);
            self += __shfl_xor(self, m, 64);
            sp   += __shfl_xor(sp, m, 64);
        }
        if (lane == 0) {
            const float npos  = (float)(hist[lab] - 1);
            const float denom = pd - __expf(self);
            lsum += __logf(denom) - (sp - self) / npos;
        }
    }
    __shared__ float w4[4];
    if (lane == 0) w4[wave] = lsum;
    __syncthreads();
    if (tid == 0)
        atomicAdd(out, (w4[0] + w4[1] + w4[2] + w4[3]) * (1.0f / (float)B_ROWS));
}

// ---------------------------------------------------------------------------
extern "C" void kernel_launch(void* const* d_in, const int* in_sizes, int n_in,
                              void* d_out, int out_size, void* d_ws, size_t ws_size,
                              hipStream_t stream) {
    const float* f      = (const float*)d_in[0];
    const float* fneg   = (const float*)d_in[1];
    const int*   labels = (const int*)d_in[2];
    float*       out    = (float*)d_out;

    char* ws = (char*)d_ws;
    // Workspace layout (bytes):
    //   G      : 12288*128*2 = 3,145,728
    //   part_d : 4096*32*4   =   524,288
    //   S      : 16*128*4    =     8,192
    //   hist   : 16*4
    __hip_bfloat16* G      = (__hip_bfloat16*)(ws);
    float*          part_d = (float*)(ws + 3145728);
    float*          S      = (float*)(ws + 3145728 + 524288);
    int*            hist   = (int*)(ws + 3145728 + 524288 + 8192);

    nrm_kernel<<<N_TOT / 4, 256, 0, stream>>>(f, fneg, G, S, hist, out);
    csum_kernel<<<B_ROWS / 128, 256, 0, stream>>>(G, labels, S, hist);

    dim3 gridS(NCHUNK, 32);   // (16, 32) = 512 blocks, 2/CU
    sim_kernel<<<gridS, 512, 0, stream>>>(G, part_d);

    fin_kernel<<<128, 256, 0, stream>>>(G, part_d, S, labels, hist, out);
}

// Round 7
// 37.129 us; speedup vs baseline: 3.2673x; 1.6718x over previous
//
#include <hip/hip_runtime.h>
#include <hip/hip_bf16.h>
#include <hip/hip_fp8.h>

// Problem constants (fixed by setup_inputs): B=4096, d=128, M=8192, C=16
#define B_ROWS 4096
#define D_K    128
#define M_ROWS 8192
#define N_TOT  12288   // B_ROWS + M_ROWS
#define NCHUNK 32      // j-chunks (grid.x of sim)
#define JT_PER_CHUNK 6 // 192 j-tiles of 64 cols / 32 chunks
#define JCOLS  64      // cols per j-tile
#define NCLS   16

typedef __attribute__((ext_vector_type(4))) int   intx4;
typedef __attribute__((ext_vector_type(8))) int   intx8;
typedef __attribute__((ext_vector_type(4))) float floatx4;

// ---------------------------------------------------------------------------
// Kernel 1: normalize rows of f / f_neg into OCP fp8-e4m3 G8[N_TOT][128].
// One wave per row; lane holds 2 floats. Block 0 zeros S/hist/out.
// ---------------------------------------------------------------------------
__global__ __launch_bounds__(256) void nrm_kernel(
    const float* __restrict__ f, const float* __restrict__ fneg,
    unsigned char* __restrict__ G8, float* __restrict__ S,
    int* __restrict__ hist, float* __restrict__ out)
{
    const int tid  = threadIdx.x;
    const int wave = tid >> 6;
    const int lane = tid & 63;
    const int row  = blockIdx.x * 4 + wave;           // grid exact: 3072*4
    if (blockIdx.x == 0) {
        #pragma unroll
        for (int k = 0; k < 8; ++k) S[tid + k * 256] = 0.f;
        if (tid < NCLS) hist[tid] = 0;
        if (tid == 0) out[0] = 0.f;
    }
    const float* src = (row < B_ROWS) ? (f + (size_t)row * D_K)
                                      : (fneg + (size_t)(row - B_ROWS) * D_K);
    float2 v = *reinterpret_cast<const float2*>(src + lane * 2);
    float ss = v.x * v.x + v.y * v.y;
    #pragma unroll
    for (int m = 1; m < 64; m <<= 1) ss += __shfl_xor(ss, m, 64);
    const float scale = 1.0f / fmaxf(sqrtf(ss), 1e-8f);   // 1/max(||x||, EPS)
    __hip_fp8_e4m3 q0(v.x * scale);
    __hip_fp8_e4m3 q1(v.y * scale);
    const unsigned short pk =
        (unsigned short)q0.__x | ((unsigned short)q1.__x << 8);
    *reinterpret_cast<unsigned short*>(G8 + (size_t)row * D_K + lane * 2) = pk;
}

// ---------------------------------------------------------------------------
// Kernel 2: per-class sums S[c][d] (f32 of fp8 values) + label histogram.
// 128 blocks (32 row-stripes x 4 d-chunks of 32 dims) x 256 thr.
// LDS partials, then global atomicAdd merge (low contention).
// ---------------------------------------------------------------------------
__global__ __launch_bounds__(256) void csum_kernel(
    const unsigned char* __restrict__ G8, const int* __restrict__ labels,
    float* __restrict__ S, int* __restrict__ hist)
{
    __shared__ float Sp[NCLS * 32];
    __shared__ int   lh[NCLS];
    const int tid    = threadIdx.x;
    const int stripe = blockIdx.x & 31;   // 128-row stripe
    const int dc     = blockIdx.x >> 5;   // 0..3 : 32-dim chunk
    #pragma unroll
    for (int k = tid; k < NCLS * 32; k += 256) Sp[k] = 0.f;
    if (tid < NCLS) lh[tid] = 0;
    __syncthreads();

    const int j0 = stripe * 128;
    if (dc == 0 && tid < 128) atomicAdd(&lh[labels[j0 + tid]], 1);

    const int d = tid & 31;
    const int w = tid >> 5;               // 0..7 row-walkers
    for (int jj = w; jj < 128; jj += 8) {
        const int j = j0 + jj;
        const int c = labels[j];
        const float v = float(reinterpret_cast<const __hip_fp8_e4m3&>(
            G8[(size_t)j * D_K + dc * 32 + d]));
        atomicAdd(&Sp[c * 32 + d], v);
    }
    __syncthreads();
    for (int k = tid; k < NCLS * 32; k += 256) {
        const int c  = k >> 5;
        const int dd = k & 31;
        atomicAdd(&S[c * D_K + dc * 32 + dd], Sp[k]);
    }
    if (dc == 0 && tid < NCLS) atomicAdd(&hist[tid], lh[tid]);
}

// ---------------------------------------------------------------------------
// Kernel 3: branch-free exp-sum GEMM via MX-FP8, K=128 in ONE MFMA.
// Grid (32, 32) = 1024 blocks x 256 thr (4 waves). Block tile 128i x 64j;
// wave tile 32i x 64j: acc 2x4 fragments of mfma_scale_f32_16x16x128_f8f6f4
// (unity E8M0 scales = 0x7F). A fragments (2 x intx8) register-resident.
// B j-tile (64 rows x 128B = 8KB) double-buffered in LDS, reg-staged with
// 16B-granule XOR swizzle (gran = slot ^ (row&7), both sides — R5/R6
// verified) so ds_read_b128 fragment reads are 2-lanes/bank (free).
// ~116 VGPR -> 4 blocks/CU co-resident: barrier stalls hide across blocks.
// Layout note: A and B loads use IDENTICAL lane->k byte mappings, so any
// K-permutation inside the fragment cancels in G*G^T.
// C/D: col(j) = lane&15, row(i) = (lane>>4)*4 + reg (shape-determined).
// ---------------------------------------------------------------------------
__global__ __launch_bounds__(256, 4) void sim_kernel(
    const unsigned char* __restrict__ G8, float* __restrict__ part_d)
{
    __shared__ unsigned char Bs[2][JCOLS * D_K];   // 2 x 8KB

    const int jc   = blockIdx.x;          // 0..31
    const int it   = blockIdx.y;          // 0..31
    const int tid  = threadIdx.x;         // 0..255
    const int wave = tid >> 6;            // 0..3 : i-quarter
    const int lane = tid & 63;
    const int i0   = it * 128 + wave * 32;

    const int r16 = lane & 15;
    const int grp = lane >> 4;            // 0..3

    // resident A fragments [a]: rows i0 + a*16 + r16, bytes k = grp*32..+31
    const unsigned char* Abase = G8 + (size_t)(i0 + r16) * D_K + grp * 32;
    intx8 afr[2];
    #pragma unroll
    for (int a = 0; a < 2; ++a)
        afr[a] = *reinterpret_cast<const intx8*>(Abase + (size_t)a * 16 * D_K);

    float dsum[2][4];
    #pragma unroll
    for (int a = 0; a < 2; ++a)
        #pragma unroll
        for (int r = 0; r < 4; ++r) dsum[a][r] = 0.f;

    // staging: 8KB tile, 256 thr x 16B x 2 rounds. LDS linear byte
    // p = s*4096 + tid*16 -> row = s*32 + tid/8, slot = tid&7;
    // source granule pre-swizzled: gran = slot ^ (row&7).
    int srcoff[2];
    #pragma unroll
    for (int s = 0; s < 2; ++s) {
        const int row  = s * 32 + (tid >> 3);
        const int gran = (tid & 7) ^ (row & 7);
        srcoff[s] = row * D_K + gran * 16;
    }

    intx4 streg[2];
    {   // prologue: tile 0 -> buf 0
        const unsigned char* src =
            G8 + (size_t)(jc * JT_PER_CHUNK) * JCOLS * D_K;
        #pragma unroll
        for (int s = 0; s < 2; ++s)
            streg[s] = *reinterpret_cast<const intx4*>(src + srcoff[s]);
        #pragma unroll
        for (int s = 0; s < 2; ++s)
            *reinterpret_cast<intx4*>(&Bs[0][0] + s * 4096 + tid * 16) =
                streg[s];
    }

    for (int t = 0; t < JT_PER_CHUNK; ++t) {
        const int cur = t & 1;
        __syncthreads();   // buf[cur] written & visible; buf[cur^1] reads done

        if (t + 1 < JT_PER_CHUNK) {
            const unsigned char* src =
                G8 + (size_t)(jc * JT_PER_CHUNK + t + 1) * JCOLS * D_K;
            #pragma unroll
            for (int s = 0; s < 2; ++s)
                streg[s] = *reinterpret_cast<const intx4*>(src + srcoff[s]);
        }

        floatx4 acc[2][4];
        #pragma unroll
        for (int a = 0; a < 2; ++a)
            #pragma unroll
            for (int b = 0; b < 4; ++b)
                acc[a][b] = (floatx4){0.f, 0.f, 0.f, 0.f};

        const unsigned char* base = &Bs[cur][0];
        #pragma unroll
        for (int b = 0; b < 4; ++b) {
            const int jloc = b * 16 + r16;
            const int sw   = jloc & 7;
            intx4 lo = *reinterpret_cast<const intx4*>(
                base + jloc * D_K + ((2 * grp)     ^ sw) * 16);
            intx4 hi = *reinterpret_cast<const intx4*>(
                base + jloc * D_K + ((2 * grp + 1) ^ sw) * 16);
            intx8 bfr;
            #pragma unroll
            for (int e = 0; e < 4; ++e) { bfr[e] = lo[e]; bfr[e + 4] = hi[e]; }
            #pragma unroll
            for (int a = 0; a < 2; ++a)
                acc[a][b] = __builtin_amdgcn_mfma_scale_f32_16x16x128_f8f6f4(
                    afr[a], bfr, acc[a][b], 0, 0,
                    0, 0x7F7F7F7F, 0, 0x7F7F7F7F);   // unity scales
        }

        // branch-free epilogue: exp-sum everything (self handled in fin)
        #pragma unroll
        for (int a = 0; a < 2; ++a)
            #pragma unroll
            for (int r = 0; r < 4; ++r) {
                float s0 = __expf(acc[a][0][r]) + __expf(acc[a][1][r]);
                float s1 = __expf(acc[a][2][r]) + __expf(acc[a][3][r]);
                dsum[a][r] += s0 + s1;
            }

        if (t + 1 < JT_PER_CHUNK) {
            #pragma unroll
            for (int s = 0; s < 2; ++s)
                *reinterpret_cast<intx4*>(
                    &Bs[cur ^ 1][0] + s * 4096 + tid * 16) = streg[s];
        }
    }

    // 16-lane (column-group) reduce
    #pragma unroll
    for (int a = 0; a < 2; ++a)
        #pragma unroll
        for (int r = 0; r < 4; ++r) {
            #pragma unroll
            for (int m = 1; m < 16; m <<= 1)
                dsum[a][r] += __shfl_xor(dsum[a][r], m, 64);
        }
    if (r16 == 0) {
        #pragma unroll
        for (int a = 0; a < 2; ++a)
            #pragma unroll
            for (int r = 0; r < 4; ++r)
                part_d[(size_t)(i0 + a * 16 + grp * 4 + r) * NCHUNK + jc] =
                    dsum[a][r];
    }
}

// ---------------------------------------------------------------------------
// Kernel 4: finalize. 128 blocks x 4 waves; each wave owns 8 rows.
// Per row: denom = sum(part) - exp(selfdot); psum = <g_i, S[lab]> - selfdot;
// loss = log(denom) - psum/npos. Block reduce -> atomicAdd(out, mean part).
// ---------------------------------------------------------------------------
__global__ __launch_bounds__(256) void fin_kernel(
    const unsigned char* __restrict__ G8, const float* __restrict__ part_d,
    const float* __restrict__ S, const int* __restrict__ labels,
    const int* __restrict__ hist, float* __restrict__ out)
{
    const int tid  = threadIdx.x;
    const int wave = tid >> 6;
    const int lane = tid & 63;

    float lsum = 0.f;
    #pragma unroll 2
    for (int rr = 0; rr < 8; ++rr) {
        const int i   = (blockIdx.x * 4 + wave) * 8 + rr;
        const int lab = labels[i];
        float pd = (lane < NCHUNK) ? part_d[(size_t)i * NCHUNK + lane] : 0.f;
        const unsigned char* gr = G8 + (size_t)i * D_K + lane * 2;
        const float f0 = float(reinterpret_cast<const __hip_fp8_e4m3&>(gr[0]));
        const float f1 = float(reinterpret_cast<const __hip_fp8_e4m3&>(gr[1]));
        float2 sv = *reinterpret_cast<const float2*>(S + lab * D_K + lane * 2);
        float self = f0 * f0 + f1 * f1;
        float sp   = f0 * sv.x + f1 * sv.y;
        #pragma unroll
        for (int m = 1; m < 64; m <<= 1) {
            pd   += __shfl_xor(pd, m, 64);
            self += __shfl_xor(self, m, 64);
            sp   += __shfl_xor(sp, m, 64);
        }
        if (lane == 0) {
            const float npos  = (float)(hist[lab] - 1);
            const float denom = pd - __expf(self);
            lsum += __logf(denom) - (sp - self) / npos;
        }
    }
    __shared__ float w4[4];
    if (lane == 0) w4[wave] = lsum;
    __syncthreads();
    if (tid == 0)
        atomicAdd(out, (w4[0] + w4[1] + w4[2] + w4[3]) * (1.0f / (float)B_ROWS));
}

// ---------------------------------------------------------------------------
extern "C" void kernel_launch(void* const* d_in, const int* in_sizes, int n_in,
                              void* d_out, int out_size, void* d_ws, size_t ws_size,
                              hipStream_t stream) {
    const float* f      = (const float*)d_in[0];
    const float* fneg   = (const float*)d_in[1];
    const int*   labels = (const int*)d_in[2];
    float*       out    = (float*)d_out;

    char* ws = (char*)d_ws;
    // Workspace layout (bytes):
    //   G8     : 12288*128   = 1,572,864
    //   part_d : 4096*32*4   =   524,288
    //   S      : 16*128*4    =     8,192
    //   hist   : 16*4
    unsigned char* G8     = (unsigned char*)(ws);
    float*         part_d = (float*)(ws + 1572864);
    float*         S      = (float*)(ws + 1572864 + 524288);
    int*           hist   = (int*)(ws + 1572864 + 524288 + 8192);

    nrm_kernel<<<N_TOT / 4, 256, 0, stream>>>(f, fneg, G8, S, hist, out);
    csum_kernel<<<128, 256, 0, stream>>>(G8, labels, S, hist);

    dim3 gridS(NCHUNK, 32);   // (32, 32) = 1024 blocks, 4/CU
    sim_kernel<<<gridS, 256, 0, stream>>>(G8, part_d);

    fin_kernel<<<128, 256, 0, stream>>>(G8, part_d, S, labels, hist, out);
}